// Round 9
// baseline (195.235 us; speedup 1.0000x reference)
//
#include <hip/hip_runtime.h>
#include <hip/hip_fp16.h>

// ---------------------------------------------------------------------------
// EmbeddingClassifier: out[32768,1000] = -arccosh(poincare_arg) * scale
// v5b: latency-bound fix. 512 blocks x 512 thr (8 waves = 4 row-groups x 2
// col-halves), 70KB dynamic LDS -> 2 blocks/CU = 16 waves/CU (50% occ).
// Each col-half runs an independent 16-tile (32-col) dbuf pipeline.
// psq staged to LDS (epilogue reads are lgkm, never drain stores); bias in
// regs; ALL LDS access via explicit addrspace(3) + integer offsets.
// (v5 -> v5b: use ext_vector f32x4 for LDS psq staging — HIP float4 class
// operator= doesn't exist for addrspace(3); ext vectors assign fine.)
// ---------------------------------------------------------------------------

#define EPSF 1e-5f

typedef _Float16 half8 __attribute__((ext_vector_type(8)));
typedef _Float16 half4v __attribute__((ext_vector_type(4)));
typedef float f32x4 __attribute__((ext_vector_type(4)));

typedef __attribute__((address_space(3))) char as3_char;
typedef __attribute__((address_space(3))) unsigned int as3_u32;
typedef __attribute__((address_space(1))) unsigned int as1_u32;
#define GLOAD16(gp, lp) __builtin_amdgcn_global_load_lds(  \
    (const as1_u32*)(gp), (as3_u32*)(lp), 16, 0, 0)

#define LDS_H8(off)  (*((__attribute__((address_space(3)))       half8*)((as3_char*)lds + (off))))
#define LDS_CH8(off) (*((__attribute__((address_space(3))) const half8*)((as3_char*)lds + (off))))
#define LDS_F16(off) (*((__attribute__((address_space(3)))    _Float16*)((as3_char*)lds + (off))))
#define LDS_F32(off) (*((__attribute__((address_space(3)))       float*)((as3_char*)lds + (off))))
#define LDS_V4(off)  (*((__attribute__((address_space(3)))       f32x4*)((as3_char*)lds + (off))))

static __device__ __forceinline__ f32x4 mfma16(half8 a, half8 b, f32x4 c) {
  return __builtin_amdgcn_mfma_f32_16x16x32_f16(a, b, c, 0, 0, 0);
}

// ws layout: proto image (1024 rows x 512B fp16, swizzled byte^=((row&7)<<4))
// + p_sq. 516 KB total (proven safe in rounds 2/4).
#define PROTO_OFF 0
#define PSQ_OFF   (1024 * 512)
#define WS_BYTES  (PSQ_OFF + 4096)

// LDS map (dynamic, 70144 B): 4 x 16KB tile bufs; x-transpose reuses [0,32K);
// psq table at 64K; cross-half norm partials at 68K.
#define PSQ_L   65536
#define PSUM_L  69632
#define LDS_SZ  70144

// ---------------------------------------------------------------------------
__global__ __launch_bounds__(256) void prep_kernel(const float* __restrict__ emb,
                                                   char* __restrict__ ws) {
  const int tid = threadIdx.x;
  const int wave = tid >> 6, lane = tid & 63;
  const int row = blockIdx.x * 4 + wave;     // 0..1023
  float4 v = {0.f, 0.f, 0.f, 0.f};
  if (row < 1000) v = ((const float4*)emb)[row * 64 + lane];
  float s = v.x * v.x + v.y * v.y + v.z * v.z + v.w * v.w;
#pragma unroll
  for (int m = 1; m < 64; m <<= 1) s += __shfl_xor(s, m, 64);
  float r  = sqrtf(s);
  float rc = fmaxf(r, EPSF);
  float e  = __expf(2.0f * rc);
  float t  = 1.0f - 2.0f / (e + 1.0f);       // tanh(rc)
  float sc = t / rc;
  float ps = t * t;
  if (row >= 1000) { sc = 0.0f; ps = 0.0f; }
  half4v h;
  h[0] = (_Float16)(v.x * sc); h[1] = (_Float16)(v.y * sc);
  h[2] = (_Float16)(v.z * sc); h[3] = (_Float16)(v.w * sc);
  const int byte = (lane * 8) ^ ((row & 7) << 4);
  *(half4v*)(ws + PROTO_OFF + row * 512 + byte) = h;
  if (lane == 0) ((float*)(ws + PSQ_OFF))[row] = ps;
}

// ---------------------------------------------------------------------------
// Fused: grid 512 x 512 thr. 64 rows/block. wave = (r = row-group, c = half).
// ---------------------------------------------------------------------------
__global__ __launch_bounds__(512, 4) void fused_kernel(
    const float* __restrict__ fea, const float* __restrict__ W,
    const float* __restrict__ bvec, const float* __restrict__ lsc,
    const char* __restrict__ ws, float* __restrict__ out) {
  extern __shared__ char lds[];
  const int tid  = threadIdx.x;
  const int wave = tid >> 6, lane = tid & 63;
  const int r = wave >> 1, c = wave & 1;
  const int g = lane >> 4, i = lane & 15;
  const int xr = (i & 7) << 4;
  const int ht = r * 64 + lane;              // id within col-half (0..255)
  const int m0 = blockIdx.x * 64;
  const int cbase = c * 32768;               // this half's two 16KB bufs

  const char* pimg = ws + PROTO_OFF;

  // ---- prologue: bias + scale regs; psq table -> LDS -----------------------
  float bl[8];
#pragma unroll
  for (int cf = 0; cf < 8; ++cf) bl[cf] = bvec[c * 128 + cf * 16 + i];
  const float sc_ln2 = fminf(__expf(lsc[0]), 100.0f) * 0.69314718055994531f;
  if (tid < 256) {
    f32x4 pq = ((const f32x4*)(ws + PSQ_OFF))[tid];
    LDS_V4(PSQ_L + tid * 16) = pq;
  }

  // ================= Phase 1: x_lin = fea @ W^T =============================
  const f32x4 z4 = {0.f, 0.f, 0.f, 0.f};
  f32x4 accW[8];
#pragma unroll
  for (int cf = 0; cf < 8; ++cf) accW[cf] = z4;

  auto stageW = [&](int kc, int boff) {      // 16KB: this half's 128 W rows
#pragma unroll
    for (int p = 0; p < 4; ++p) {
      const int u = p * 256 + ht;            // 1024 granules of 8 floats
      const int nl = u >> 3, k8 = u & 7;
      const float4* src = (const float4*)(W + (size_t)(c * 128 + nl) * 256 +
                                          kc * 64 + k8 * 8);
      float4 v0 = src[0], v1 = src[1];
      half8 h = {(_Float16)v0.x, (_Float16)v0.y, (_Float16)v0.z, (_Float16)v0.w,
                 (_Float16)v1.x, (_Float16)v1.y, (_Float16)v1.z, (_Float16)v1.w};
      LDS_H8(boff + nl * 128 + ((k8 * 16) ^ ((nl & 7) << 4))) = h;
    }
  };
  auto mfmaW = [&](int kc, int boff) {
#pragma unroll
    for (int ksl = 0; ksl < 2; ++ksl) {
      const float4* ap = (const float4*)(fea + (size_t)(m0 + r * 16 + i) * 256 +
                                         kc * 64 + ksl * 32 + g * 8);
      float4 a0 = ap[0], a1 = ap[1];
      half8 a = {(_Float16)a0.x, (_Float16)a0.y, (_Float16)a0.z, (_Float16)a0.w,
                 (_Float16)a1.x, (_Float16)a1.y, (_Float16)a1.z, (_Float16)a1.w};
#pragma unroll
      for (int cf = 0; cf < 8; ++cf) {
        half8 b = LDS_CH8(boff + (cf * 16 + i) * 128 + ((ksl * 64 + g * 16) ^ xr));
        accW[cf] = mfma16(a, b, accW[cf]);
      }
    }
  };

  stageW(0, cbase);         __syncthreads();
  stageW(1, cbase + 16384); mfmaW(0, cbase);         __syncthreads();
  stageW(2, cbase);         mfmaW(1, cbase + 16384); __syncthreads();
  stageW(3, cbase + 16384); mfmaW(2, cbase);         __syncthreads();
  mfmaW(3, cbase + 16384);  __syncthreads();   // all W reads done before x reuse

  // ---- epilogue1: bias, cross-half row norms, expmap scale -----------------
  float ssum[4] = {0.f, 0.f, 0.f, 0.f};
#pragma unroll
  for (int cf = 0; cf < 8; ++cf)
#pragma unroll
    for (int reg = 0; reg < 4; ++reg) {
      accW[cf][reg] += bl[cf];
      ssum[reg] = fmaf(accW[cf][reg], accW[cf][reg], ssum[reg]);
    }
#pragma unroll
  for (int m = 1; m < 16; m <<= 1)
#pragma unroll
    for (int reg = 0; reg < 4; ++reg) ssum[reg] += __shfl_xor(ssum[reg], m, 64);
  if (i == 0) {
#pragma unroll
    for (int reg = 0; reg < 4; ++reg)
      LDS_F32(PSUM_L + (c * 64 + r * 16 + g * 4 + reg) * 4) = ssum[reg];
  }
  __syncthreads();

  float scl[4], xsv[4];
#pragma unroll
  for (int reg = 0; reg < 4; ++reg) {
    const int row = r * 16 + g * 4 + reg;
    float s  = LDS_F32(PSUM_L + row * 4) + LDS_F32(PSUM_L + (64 + row) * 4);
    float rn = sqrtf(s);
    float rc = fmaxf(rn, EPSF);
    float e  = __expf(2.0f * rc);
    float t  = 1.0f - 2.0f / (e + 1.0f);
    scl[reg] = t / rc;
    xsv[reg] = t * t;                        // x_sq in f32 (exact denom clamp)
  }

  // ---- x (f16, swizzled) into [0,32K); then A-frags to regs ----------------
#pragma unroll
  for (int cf = 0; cf < 8; ++cf)
#pragma unroll
    for (int reg = 0; reg < 4; ++reg) {
      const int row = r * 16 + g * 4 + reg;          // 0..63
      const int col = c * 128 + cf * 16 + i;
      LDS_F16(row * 512 + ((col * 2) ^ ((row & 7) << 4))) =
          (_Float16)(accW[cf][reg] * scl[reg]);
    }
  __syncthreads();                            // x fully written
  half8 A[8];
#pragma unroll
  for (int ks = 0; ks < 8; ++ks)
    A[ks] = LDS_CH8((r * 16 + i) * 512 + ((ks * 64 + g * 16) ^ xr));
  asm volatile("s_waitcnt lgkmcnt(0)" ::: "memory");
  __builtin_amdgcn_sched_barrier(0);
  __syncthreads();                            // A-reads landed before buf reuse

  // ================= Phase 2: per-half 16 tiles of 32 cols ==================
  auto stageP = [&](int t, int boff) {        // 16KB tile, 4 waves x 4 chunks
#pragma unroll
    for (int p = 0; p < 4; ++p) {
      const int chunk = p * 4 + r;
      GLOAD16(pimg + ((size_t)(c * 512 + t * 32) * 512) + chunk * 1024 + lane * 16,
              (as3_char*)lds + boff + chunk * 1024);
    }
  };
  stageP(0, cbase);
  asm volatile("s_waitcnt vmcnt(0)" ::: "memory");
  __builtin_amdgcn_s_barrier();
  __builtin_amdgcn_sched_barrier(0);

  for (int t = 0; t < 16; ++t) {
    const int cur = cbase + (t & 1) * 16384;
    const int nxt = cbase + ((t + 1) & 1) * 16384;

    float psq[2];
#pragma unroll
    for (int cf = 0; cf < 2; ++cf)
      psq[cf] = LDS_F32(PSQ_L + (c * 512 + t * 32 + cf * 16 + i) * 4);

    if (t < 15) stageP(t + 1, nxt);           // DMAs issued before everything

    f32x4 acc[2] = {z4, z4};
#pragma unroll
    for (int ks = 0; ks < 8; ++ks)
#pragma unroll
      for (int cf = 0; cf < 2; ++cf) {
        half8 b = LDS_CH8(cur + (cf * 16 + i) * 512 + ((ks * 64 + g * 16) ^ xr));
        acc[cf] = mfma16(A[ks], b, acc[cf]);
      }

#pragma unroll
    for (int cf = 0; cf < 2; ++cf) {
      const float ps = psq[cf], omp = 1.0f - ps;
      const int col = c * 512 + t * 32 + cf * 16 + i;
#pragma unroll
      for (int reg = 0; reg < 4; ++reg) {
        const float xs   = xsv[reg];
        const float diff = fmaxf(fmaf(-2.0f, acc[cf][reg], xs + ps), 0.0f);
        const float den  = fmaxf((1.0f - xs) * omp, EPSF);
        const float arg  = fmaxf(fmaf(2.0f * diff, __builtin_amdgcn_rcpf(den), 1.0f),
                                 1.0f + EPSF);
        const float sq   = __builtin_amdgcn_sqrtf(fmaf(arg, arg, -1.0f));
        const float dist = __log2f(arg + sq);
        if (col < 1000)
          out[(size_t)(m0 + r * 16 + g * 4 + reg) * 1000 + col] = -dist * sc_ln2;
      }
    }
    if (t < 15) {
      // retires this tile's 4 DMAs (and >=1-tile-old stores); leaves the 8
      // fresh stores in flight across the barrier
      asm volatile("s_waitcnt vmcnt(8)" ::: "memory");
      __builtin_amdgcn_s_barrier();
      __builtin_amdgcn_sched_barrier(0);
    }
  }
}

// ---------------------------------------------------------------------------
// Fallback (ws-free, fp32) — only if ws_size < WS_BYTES. Insurance.
// ---------------------------------------------------------------------------
__global__ __launch_bounds__(256) void fallback_kernel(
    const float* __restrict__ fea, const float* __restrict__ W,
    const float* __restrict__ b, const float* __restrict__ emb,
    const float* __restrict__ lsc, float* __restrict__ out) {
  __shared__ float fr_[16][256];
  __shared__ float xr_[16][256];
  __shared__ float xs_[16];
  const int tid  = threadIdx.x;
  const int row0 = blockIdx.x * 16;

  for (int u = tid; u < 16 * 256; u += 256)
    fr_[u >> 8][u & 255] = fea[(size_t)(row0 + (u >> 8)) * 256 + (u & 255)];
  __syncthreads();

  float acc[16];
  const float bj = b[tid];
#pragma unroll
  for (int r = 0; r < 16; ++r) acc[r] = bj;
  for (int k = 0; k < 256; ++k) {
    const float wv = W[(size_t)tid * 256 + k];
#pragma unroll
    for (int r = 0; r < 16; ++r) acc[r] = fmaf(fr_[r][k], wv, acc[r]);
  }
#pragma unroll
  for (int r = 0; r < 16; ++r) xr_[r][tid] = acc[r];
  __syncthreads();

  if (tid < 16) {
    float s = 0.f;
    for (int k = 0; k < 256; ++k) s = fmaf(xr_[tid][k], xr_[tid][k], s);
    const float rn = sqrtf(s), rc = fmaxf(rn, EPSF);
    const float e = __expf(2.f * rc), t = 1.f - 2.f / (e + 1.f);
    xs_[tid] = t * t;
    fr_[tid][0] = t / rc;
  }
  __syncthreads();
  for (int u = tid; u < 16 * 256; u += 256)
    xr_[u >> 8][u & 255] *= fr_[u >> 8][0];
  __syncthreads();

  const float sc_out = fminf(__expf(lsc[0]), 100.0f);
  for (int cc = tid; cc < 1000; cc += 256) {
    float s = 0.f;
    for (int k = 0; k < 256; ++k) {
      const float e0 = emb[(size_t)cc * 256 + k];
      s = fmaf(e0, e0, s);
    }
    const float rn = sqrtf(s), rc = fmaxf(rn, EPSF);
    const float e = __expf(2.f * rc), t = 1.f - 2.f / (e + 1.f);
    const float psc = t / rc, ps = t * t, omp = 1.f - ps;
    float dots[16];
#pragma unroll
    for (int r = 0; r < 16; ++r) dots[r] = 0.f;
    for (int k = 0; k < 256; ++k) {
      const float pk = emb[(size_t)cc * 256 + k] * psc;
#pragma unroll
      for (int r = 0; r < 16; ++r) dots[r] = fmaf(xr_[r][k], pk, dots[r]);
    }
#pragma unroll
    for (int r = 0; r < 16; ++r) {
      const float xs = xs_[r];
      const float diff = fmaxf(xs + ps - 2.f * dots[r], 0.f);
      const float den  = fmaxf((1.f - xs) * omp, EPSF);
      const float arg  = fmaxf(1.f + 2.f * diff / den, 1.f + EPSF);
      const float d    = logf(arg + sqrtf(fmaf(arg, arg, -1.f)));
      out[(size_t)(row0 + r) * 1000 + cc] = -d * sc_out;
    }
  }
}

// ---------------------------------------------------------------------------
extern "C" void kernel_launch(void* const* d_in, const int* in_sizes, int n_in,
                              void* d_out, int out_size, void* d_ws, size_t ws_size,
                              hipStream_t stream) {
  (void)in_sizes; (void)n_in; (void)out_size;
  const float* fea = (const float*)d_in[0];
  const float* W   = (const float*)d_in[1];
  const float* b   = (const float*)d_in[2];
  const float* emb = (const float*)d_in[3];
  const float* ls  = (const float*)d_in[4];
  float* out = (float*)d_out;
  char*  ws  = (char*)d_ws;

  if (ws_size >= (size_t)WS_BYTES) {
    (void)hipFuncSetAttribute((const void*)fused_kernel,
                              hipFuncAttributeMaxDynamicSharedMemorySize, LDS_SZ);
    prep_kernel<<<256, 256, 0, stream>>>(emb, ws);
    fused_kernel<<<512, 512, LDS_SZ, stream>>>(fea, W, b, ls, ws, out);
  } else {
    fallback_kernel<<<2048, 256, 0, stream>>>(fea, W, b, emb, ls, out);
  }
}